// Round 1
// baseline (1158.849 us; speedup 1.0000x reference)
//
#include <hip/hip_runtime.h>
#include <math.h>

// ---------------- CSR build ----------------

__global__ void k_degree(const int* __restrict__ dst, int* __restrict__ deg, int E) {
  int e = blockIdx.x * 256 + threadIdx.x;
  if (e < E) atomicAdd(&deg[dst[e]], 1);
}

__global__ void k_scan1(const int* __restrict__ deg, int* __restrict__ part,
                        int* __restrict__ bs, int N) {
  __shared__ int s[256];
  int gid = blockIdx.x * 256 + threadIdx.x;
  int v = (gid < N) ? deg[gid] : 0;
  s[threadIdx.x] = v;
  __syncthreads();
  for (int off = 1; off < 256; off <<= 1) {
    int t = (threadIdx.x >= off) ? s[threadIdx.x - off] : 0;
    __syncthreads();
    s[threadIdx.x] += t;
    __syncthreads();
  }
  if (gid < N) part[gid] = s[threadIdx.x] - v;     // exclusive within block
  if (threadIdx.x == 255) bs[blockIdx.x] = s[255]; // block total
}

__global__ void k_scan2(int* __restrict__ bs, int nb) {
  __shared__ int s[256];
  int v = (threadIdx.x < nb) ? bs[threadIdx.x] : 0;
  s[threadIdx.x] = v;
  __syncthreads();
  for (int off = 1; off < 256; off <<= 1) {
    int t = (threadIdx.x >= off) ? s[threadIdx.x - off] : 0;
    __syncthreads();
    s[threadIdx.x] += t;
    __syncthreads();
  }
  if (threadIdx.x < nb) bs[threadIdx.x] = s[threadIdx.x] - v; // exclusive block offsets
}

__global__ void k_scan3(int* __restrict__ rowptr, const int* __restrict__ bs,
                        int* __restrict__ cursor, int N, int E) {
  int gid = blockIdx.x * 256 + threadIdx.x;
  if (gid < N) {
    int v = rowptr[gid] + bs[blockIdx.x];
    rowptr[gid] = v;
    cursor[gid] = v;
  }
  if (gid == 0) rowptr[N] = E;
}

__global__ void k_fill(const int* __restrict__ src, const int* __restrict__ dst,
                       int* __restrict__ cursor, int* __restrict__ col, int E) {
  int e = blockIdx.x * 256 + threadIdx.x;
  if (e < E) {
    int p = atomicAdd(&cursor[dst[e]], 1);
    col[p] = src[e];
  }
}

// ---------------- dual GEMM: xl = h@Wl, xr = h@Wr, permuted [N][C=64][H=4] ----------------

#define GR 16
__global__ __launch_bounds__(256) void k_gemm2(const float* __restrict__ h,
                                               const float* __restrict__ Wl,
                                               const float* __restrict__ Wr,
                                               float* __restrict__ xl,
                                               float* __restrict__ xr, int N) {
  __shared__ __align__(16) float xs[GR][64];
  int f = threadIdx.x; // output column 0..255  (f = head*64 + chan)
  int r0 = blockIdx.x * GR;
  for (int i = threadIdx.x; i < GR * 64; i += 256) {
    int r = i >> 6, c = i & 63;
    int row = r0 + r;
    xs[r][c] = (row < N) ? h[(size_t)row * 64 + c] : 0.f;
  }
  __syncthreads();
  float accL[GR], accR[GR];
#pragma unroll
  for (int r = 0; r < GR; ++r) { accL[r] = 0.f; accR[r] = 0.f; }
  for (int k = 0; k < 64; k += 4) {
    float wl0 = Wl[(k + 0) * 256 + f], wl1 = Wl[(k + 1) * 256 + f];
    float wl2 = Wl[(k + 2) * 256 + f], wl3 = Wl[(k + 3) * 256 + f];
    float wr0 = Wr[(k + 0) * 256 + f], wr1 = Wr[(k + 1) * 256 + f];
    float wr2 = Wr[(k + 2) * 256 + f], wr3 = Wr[(k + 3) * 256 + f];
#pragma unroll
    for (int r = 0; r < GR; ++r) {
      float4 xv = *(const float4*)&xs[r][k];
      accL[r] = fmaf(xv.x, wl0, accL[r]);
      accL[r] = fmaf(xv.y, wl1, accL[r]);
      accL[r] = fmaf(xv.z, wl2, accL[r]);
      accL[r] = fmaf(xv.w, wl3, accL[r]);
      accR[r] = fmaf(xv.x, wr0, accR[r]);
      accR[r] = fmaf(xv.y, wr1, accR[r]);
      accR[r] = fmaf(xv.z, wr2, accR[r]);
      accR[r] = fmaf(xv.w, wr3, accR[r]);
    }
  }
  int c = f & 63, hh = f >> 6;
  int off = c * 4 + hh; // permuted layout: [node][chan][head]
#pragma unroll
  for (int r = 0; r < GR; ++r) {
    int row = r0 + r;
    if (row < N) {
      xl[(size_t)row * 256 + off] = accL[r];
      xr[(size_t)row * 256 + off] = accR[r];
    }
  }
}

// ---------------- GATv2: wave per node, online softmax ----------------

__global__ __launch_bounds__(256) void k_gat(const float* __restrict__ xl,
                                             const float* __restrict__ xr,
                                             const float* __restrict__ att,
                                             const float* __restrict__ bias,
                                             const int* __restrict__ rowptr,
                                             const int* __restrict__ col,
                                             float* __restrict__ out, int N) {
  int node = blockIdx.x * 4 + (threadIdx.x >> 6);
  int lane = threadIdx.x & 63;
  if (node >= N) return;
  // att is [H=4][C=64]; lane=channel needs att[h][lane]
  float a0 = att[lane], a1 = att[64 + lane], a2 = att[128 + lane], a3 = att[192 + lane];
  const float4 xr4 = *(const float4*)(xr + (size_t)node * 256 + lane * 4);
  int beg = rowptr[node], end = rowptr[node + 1];
  float m0 = -INFINITY, m1 = -INFINITY, m2 = -INFINITY, m3 = -INFINITY;
  float l0 = 0.f, l1 = 0.f, l2 = 0.f, l3 = 0.f;
  float o0 = 0.f, o1 = 0.f, o2 = 0.f, o3 = 0.f;
  // e == beg-1 encodes the self loop (src = node); then CSR edges
  for (int e = beg - 1; e < end; ++e) {
    int src = (e < beg) ? node : col[e];
    float4 v = *(const float4*)(xl + (size_t)src * 256 + lane * 4);
    float sx = v.x + xr4.x, sy = v.y + xr4.y, sz = v.z + xr4.z, sw = v.w + xr4.w;
    sx = (sx > 0.f) ? sx : 0.2f * sx;
    sy = (sy > 0.f) ? sy : 0.2f * sy;
    sz = (sz > 0.f) ? sz : 0.2f * sz;
    sw = (sw > 0.f) ? sw : 0.2f * sw;
    float p0 = sx * a0, p1 = sy * a1, p2 = sz * a2, p3 = sw * a3;
#pragma unroll
    for (int off = 32; off > 0; off >>= 1) {
      p0 += __shfl_xor(p0, off, 64);
      p1 += __shfl_xor(p1, off, 64);
      p2 += __shfl_xor(p2, off, 64);
      p3 += __shfl_xor(p3, off, 64);
    }
    // online softmax update per head
    float nm, sc, w;
    nm = fmaxf(m0, p0); sc = __expf(m0 - nm); w = __expf(p0 - nm);
    l0 = l0 * sc + w; o0 = o0 * sc + w * v.x; m0 = nm;
    nm = fmaxf(m1, p1); sc = __expf(m1 - nm); w = __expf(p1 - nm);
    l1 = l1 * sc + w; o1 = o1 * sc + w * v.y; m1 = nm;
    nm = fmaxf(m2, p2); sc = __expf(m2 - nm); w = __expf(p2 - nm);
    l2 = l2 * sc + w; o2 = o2 * sc + w * v.z; m2 = nm;
    nm = fmaxf(m3, p3); sc = __expf(m3 - nm); w = __expf(p3 - nm);
    l3 = l3 * sc + w; o3 = o3 * sc + w * v.w; m3 = nm;
  }
  float res = 0.25f * (o0 / l0 + o1 / l1 + o2 / l2 + o3 / l3) + bias[lane];
  out[(size_t)node * 64 + lane] = res;
}

// ---------------- BN stats + apply (+GELU +residual) ----------------

__global__ __launch_bounds__(256) void k_bn_stats(const float* __restrict__ h,
                                                  float* __restrict__ sums, int N) {
  // sums[0..63] = sum, sums[64..127] = sum of squares
  int c = threadIdx.x & 63;
  int rl = threadIdx.x >> 6; // 0..3
  float s = 0.f, q = 0.f;
  for (int n = blockIdx.x * 4 + rl; n < N; n += gridDim.x * 4) {
    float v = h[(size_t)n * 64 + c];
    s += v;
    q += v * v;
  }
  __shared__ float ls[256], lq[256];
  ls[threadIdx.x] = s;
  lq[threadIdx.x] = q;
  __syncthreads();
  if (rl == 0) {
    s = ls[c] + ls[64 + c] + ls[128 + c] + ls[192 + c];
    q = lq[c] + lq[64 + c] + lq[128 + c] + lq[192 + c];
    atomicAdd(&sums[c], s);
    atomicAdd(&sums[64 + c], q);
  }
}

__global__ __launch_bounds__(256) void k_bn_apply(const float* __restrict__ gat,
                                                  const float* __restrict__ sums,
                                                  const float* __restrict__ g,
                                                  const float* __restrict__ be,
                                                  const float* __restrict__ resid,
                                                  float* __restrict__ out,
                                                  int total, float inv_n) {
  int idx = blockIdx.x * 256 + threadIdx.x;
  if (idx >= total) return;
  int c = idx & 63;
  float mu = sums[c] * inv_n;
  float var = sums[64 + c] * inv_n - mu * mu;
  float inv = rsqrtf(var + 1e-5f);
  float v = g[c] * (gat[idx] - mu) * inv + be[c];
  float ge = 0.5f * v * (1.f + erff(v * 0.70710678118654752f)); // exact GELU
  out[idx] = ge + (resid ? resid[idx] : 0.f);
}

// ---------------- pooling + heads ----------------

__global__ __launch_bounds__(256) void k_pool(const float* __restrict__ h,
                                              const int* __restrict__ batch,
                                              float* __restrict__ pool, int total) {
  int idx = blockIdx.x * 256 + threadIdx.x;
  if (idx >= total) return;
  int n = idx >> 6, c = idx & 63;
  atomicAdd(&pool[(size_t)batch[n] * 64 + c], h[idx]);
}

__global__ void k_head(const float* __restrict__ pool, const float* __restrict__ Wmu,
                       const float* __restrict__ bmu, const float* __restrict__ Wlv,
                       const float* __restrict__ blv, float* __restrict__ out, int G) {
  int g = blockIdx.x;
  int c = threadIdx.x; // 64 threads
  __shared__ float row[64];
  row[c] = pool[(size_t)g * 64 + c];
  __syncthreads();
  float am = 0.f, al = 0.f;
  for (int k = 0; k < 64; ++k) {
    float r = row[k];
    am = fmaf(r, Wmu[k * 64 + c], am);
    al = fmaf(r, Wlv[k * 64 + c], al);
  }
  out[(size_t)g * 64 + c] = am + bmu[c];
  out[(size_t)G * 64 + (size_t)g * 64 + c] = al + blv[c];
}

// ---------------- launch ----------------

extern "C" void kernel_launch(void* const* d_in, const int* in_sizes, int n_in,
                              void* d_out, int out_size, void* d_ws, size_t ws_size,
                              hipStream_t stream) {
  const float* x    = (const float*)d_in[0];
  const int* esrc   = (const int*)d_in[1];
  const int* edst   = (const int*)d_in[2];
  const int* batch  = (const int*)d_in[3];
  const float* Wl[3]  = {(const float*)d_in[5],  (const float*)d_in[11], (const float*)d_in[17]};
  const float* Wr[3]  = {(const float*)d_in[6],  (const float*)d_in[12], (const float*)d_in[18]};
  const float* att[3] = {(const float*)d_in[7],  (const float*)d_in[13], (const float*)d_in[19]};
  const float* bia[3] = {(const float*)d_in[8],  (const float*)d_in[14], (const float*)d_in[20]};
  const float* gam[3] = {(const float*)d_in[9],  (const float*)d_in[15], (const float*)d_in[21]};
  const float* bet[3] = {(const float*)d_in[10], (const float*)d_in[16], (const float*)d_in[22]};
  const float* Wmu = (const float*)d_in[23];
  const float* bmu = (const float*)d_in[24];
  const float* Wlv = (const float*)d_in[25];
  const float* blv = (const float*)d_in[26];
  float* out = (float*)d_out;

  const int N = in_sizes[0] / 64;
  const int E = in_sizes[1];
  const int G = out_size / 128;

  // workspace carve (256B aligned)
  char* p = (char*)d_ws;
  auto alloc = [&](size_t bytes) -> void* {
    void* r = (void*)p;
    p += (bytes + 255) & ~(size_t)255;
    return r;
  };
  float* xl     = (float*)alloc((size_t)N * 256 * 4);
  float* xr     = (float*)alloc((size_t)N * 256 * 4);
  float* hA     = (float*)alloc((size_t)N * 64 * 4);
  float* hB     = (float*)alloc((size_t)N * 64 * 4);
  float* gat    = (float*)alloc((size_t)N * 64 * 4);
  int*   rowptr = (int*)alloc((size_t)(N + 1) * 4);
  int*   cursor = (int*)alloc((size_t)N * 4);
  int*   deg    = (int*)alloc((size_t)N * 4);
  int*   bs     = (int*)alloc(256 * 4);
  int*   col    = (int*)alloc((size_t)E * 4);
  float* bnsum  = (float*)alloc(128 * 4);
  float* pool   = (float*)alloc((size_t)G * 64 * 4);

  const int nbN   = (N + 255) / 256;       // scan blocks
  const int nbE   = (E + 255) / 256;
  const int nbGm  = (N + GR - 1) / GR;     // gemm blocks
  const int nbGat = (N + 3) / 4;
  const int nbEl  = (N * 64 + 255) / 256;  // elementwise blocks
  const float inv_n = 1.f / (float)N;

  // ---- CSR build (dst identical for all layers) ----
  hipMemsetAsync(deg, 0, (size_t)N * 4, stream);
  k_degree<<<nbE, 256, 0, stream>>>(edst, deg, E);
  k_scan1<<<nbN, 256, 0, stream>>>(deg, rowptr, bs, N);
  k_scan2<<<1, 256, 0, stream>>>(bs, nbN);
  k_scan3<<<nbN, 256, 0, stream>>>(rowptr, bs, cursor, N, E);
  k_fill<<<nbE, 256, 0, stream>>>(esrc, edst, cursor, col, E);

  // ---- 3 GATv2 + BN + GELU (+res) layers ----
  const float* hin = x;
  float* houts[3] = {hA, hB, hA};
  for (int L = 0; L < 3; ++L) {
    float* hout = houts[L];
    const float* resid = (L == 0) ? nullptr : hin;
    k_gemm2<<<nbGm, 256, 0, stream>>>(hin, Wl[L], Wr[L], xl, xr, N);
    k_gat<<<nbGat, 256, 0, stream>>>(xl, xr, att[L], bia[L], rowptr, col, gat, N);
    hipMemsetAsync(bnsum, 0, 128 * 4, stream);
    k_bn_stats<<<256, 256, 0, stream>>>(gat, bnsum, N);
    k_bn_apply<<<nbEl, 256, 0, stream>>>(gat, bnsum, gam[L], bet[L], resid, hout, N * 64, inv_n);
    hin = hout;
  }

  // ---- pool + heads ----
  hipMemsetAsync(pool, 0, (size_t)G * 64 * 4, stream);
  k_pool<<<nbEl, 256, 0, stream>>>(hin, batch, pool, N * 64);
  k_head<<<G, 64, 0, stream>>>(pool, Wmu, bmu, Wlv, blv, out, G);
}

// Round 2
// 762.105 us; speedup vs baseline: 1.5206x; 1.5206x over previous
//
#include <hip/hip_runtime.h>
#include <math.h>

// ---------------- helpers ----------------

static __device__ __forceinline__ unsigned short f2bf(float f) {
  unsigned u = __float_as_uint(f);
  unsigned r = (u + 0x7FFF + ((u >> 16) & 1)) >> 16; // RNE
  return (unsigned short)r;
}
static __device__ __forceinline__ float bf2f(unsigned short b) {
  return __uint_as_float(((unsigned)b) << 16);
}

// ---------------- CSR build ----------------

__global__ void k_degree(const int* __restrict__ dst, int* __restrict__ deg, int E) {
  int e = blockIdx.x * 256 + threadIdx.x;
  if (e < E) atomicAdd(&deg[dst[e]], 1);
}

__global__ void k_scan1(const int* __restrict__ deg, int* __restrict__ part,
                        int* __restrict__ bs, int N) {
  __shared__ int s[256];
  int gid = blockIdx.x * 256 + threadIdx.x;
  int v = (gid < N) ? deg[gid] : 0;
  s[threadIdx.x] = v;
  __syncthreads();
  for (int off = 1; off < 256; off <<= 1) {
    int t = (threadIdx.x >= off) ? s[threadIdx.x - off] : 0;
    __syncthreads();
    s[threadIdx.x] += t;
    __syncthreads();
  }
  if (gid < N) part[gid] = s[threadIdx.x] - v;
  if (threadIdx.x == 255) bs[blockIdx.x] = s[255];
}

__global__ void k_scan2(int* __restrict__ bs, int nb) {
  __shared__ int s[256];
  int v = (threadIdx.x < nb) ? bs[threadIdx.x] : 0;
  s[threadIdx.x] = v;
  __syncthreads();
  for (int off = 1; off < 256; off <<= 1) {
    int t = (threadIdx.x >= off) ? s[threadIdx.x - off] : 0;
    __syncthreads();
    s[threadIdx.x] += t;
    __syncthreads();
  }
  if (threadIdx.x < nb) bs[threadIdx.x] = s[threadIdx.x] - v;
}

__global__ void k_scan3(int* __restrict__ rowptr, const int* __restrict__ bs,
                        int* __restrict__ cursor, int N, int E) {
  int gid = blockIdx.x * 256 + threadIdx.x;
  if (gid < N) {
    int v = rowptr[gid] + bs[blockIdx.x];
    rowptr[gid] = v;
    cursor[gid] = v;
  }
  if (gid == 0) rowptr[N] = E;
}

__global__ void k_fill(const int* __restrict__ src, const int* __restrict__ dst,
                       int* __restrict__ cursor, int* __restrict__ col, int E) {
  int e = blockIdx.x * 256 + threadIdx.x;
  if (e < E) {
    int p = atomicAdd(&cursor[dst[e]], 1);
    col[p] = src[e];
  }
}

// ---------------- dual GEMM: xl(bf16) = h@Wl, xr(f32) = h@Wr, natural [N][H*C] ----------------

#define GR 16
__global__ __launch_bounds__(256) void k_gemm2(const float* __restrict__ h,
                                               const float* __restrict__ Wl,
                                               const float* __restrict__ Wr,
                                               unsigned short* __restrict__ xlb,
                                               float* __restrict__ xr, int N) {
  __shared__ __align__(16) float xs[GR][64];
  int f = threadIdx.x; // output column 0..255 (f = head*64 + chan, natural)
  int r0 = blockIdx.x * GR;
  for (int i = threadIdx.x; i < GR * 64; i += 256) {
    int r = i >> 6, c = i & 63;
    int row = r0 + r;
    xs[r][c] = (row < N) ? h[(size_t)row * 64 + c] : 0.f;
  }
  __syncthreads();
  float accL[GR], accR[GR];
#pragma unroll
  for (int r = 0; r < GR; ++r) { accL[r] = 0.f; accR[r] = 0.f; }
  for (int k = 0; k < 64; k += 4) {
    float wl0 = Wl[(k + 0) * 256 + f], wl1 = Wl[(k + 1) * 256 + f];
    float wl2 = Wl[(k + 2) * 256 + f], wl3 = Wl[(k + 3) * 256 + f];
    float wr0 = Wr[(k + 0) * 256 + f], wr1 = Wr[(k + 1) * 256 + f];
    float wr2 = Wr[(k + 2) * 256 + f], wr3 = Wr[(k + 3) * 256 + f];
#pragma unroll
    for (int r = 0; r < GR; ++r) {
      float4 xv = *(const float4*)&xs[r][k];
      accL[r] = fmaf(xv.x, wl0, accL[r]);
      accL[r] = fmaf(xv.y, wl1, accL[r]);
      accL[r] = fmaf(xv.z, wl2, accL[r]);
      accL[r] = fmaf(xv.w, wl3, accL[r]);
      accR[r] = fmaf(xv.x, wr0, accR[r]);
      accR[r] = fmaf(xv.y, wr1, accR[r]);
      accR[r] = fmaf(xv.z, wr2, accR[r]);
      accR[r] = fmaf(xv.w, wr3, accR[r]);
    }
  }
#pragma unroll
  for (int r = 0; r < GR; ++r) {
    int row = r0 + r;
    if (row < N) {
      xlb[(size_t)row * 256 + f] = f2bf(accL[r]);
      xr[(size_t)row * 256 + f] = accR[r];
    }
  }
}

// ---------------- GATv2: wave per node, head-major lanes, online softmax ----------------
// lane l: head h = l>>4, channels c0 = 4*(l&15). Natural [H][C] layout => lane
// reads flat offset 4*l. Score reduce = 4 shfl within 16-lane group.

__global__ __launch_bounds__(256) void k_gat(const unsigned short* __restrict__ xlb,
                                             const float* __restrict__ xr,
                                             const float* __restrict__ att,
                                             const float* __restrict__ bias,
                                             const int* __restrict__ rowptr,
                                             const int* __restrict__ col,
                                             float* __restrict__ out, int N) {
  int node = blockIdx.x * 4 + (threadIdx.x >> 6);
  int lane = threadIdx.x & 63;
  if (node >= N) return;
  const float4 a4 = *(const float4*)(att + lane * 4);
  const float4 xr4 = *(const float4*)(xr + (size_t)node * 256 + lane * 4);
  int beg = rowptr[node], end = rowptr[node + 1];
  float m = -INFINITY, lsum = 0.f;
  float ox = 0.f, oy = 0.f, oz = 0.f, ow = 0.f;
  // prefetch pipeline: first iteration is the self loop
  ushort4 vb_next = *(const ushort4*)(xlb + (size_t)node * 256 + lane * 4);
  for (int e = beg; e <= end; ++e) {
    ushort4 vb = vb_next;
    if (e < end) {
      int s2 = col[e];
      vb_next = *(const ushort4*)(xlb + (size_t)s2 * 256 + lane * 4);
    }
    float vx = bf2f(vb.x), vy = bf2f(vb.y), vz = bf2f(vb.z), vw = bf2f(vb.w);
    float sx = vx + xr4.x, sy = vy + xr4.y, sz = vz + xr4.z, sw = vw + xr4.w;
    sx = (sx > 0.f) ? sx : 0.2f * sx;
    sy = (sy > 0.f) ? sy : 0.2f * sy;
    sz = (sz > 0.f) ? sz : 0.2f * sz;
    sw = (sw > 0.f) ? sw : 0.2f * sw;
    float p = sx * a4.x;
    p = fmaf(sy, a4.y, p);
    p = fmaf(sz, a4.z, p);
    p = fmaf(sw, a4.w, p);
    p += __shfl_xor(p, 1, 64);
    p += __shfl_xor(p, 2, 64);
    p += __shfl_xor(p, 4, 64);
    p += __shfl_xor(p, 8, 64);
    float nm = fmaxf(m, p);
    float sc = __expf(m - nm);
    float w = __expf(p - nm);
    lsum = lsum * sc + w;
    ox = fmaf(w, vx, ox * sc);
    oy = fmaf(w, vy, oy * sc);
    oz = fmaf(w, vz, oz * sc);
    ow = fmaf(w, vw, ow * sc);
    m = nm;
  }
  float inv = 1.f / lsum;
  float rx = ox * inv, ry = oy * inv, rz = oz * inv, rw = ow * inv;
  // sum across the 4 head groups (xor 16, 32)
  rx += __shfl_xor(rx, 16, 64); rx += __shfl_xor(rx, 32, 64);
  ry += __shfl_xor(ry, 16, 64); ry += __shfl_xor(ry, 32, 64);
  rz += __shfl_xor(rz, 16, 64); rz += __shfl_xor(rz, 32, 64);
  rw += __shfl_xor(rw, 16, 64); rw += __shfl_xor(rw, 32, 64);
  if (lane < 16) {
    float4 b4 = *(const float4*)(bias + lane * 4);
    float4 res;
    res.x = 0.25f * rx + b4.x;
    res.y = 0.25f * ry + b4.y;
    res.z = 0.25f * rz + b4.z;
    res.w = 0.25f * rw + b4.w;
    *(float4*)(out + (size_t)node * 64 + lane * 4) = res;
  }
}

// ---------------- BN stats + apply (+GELU +residual) ----------------

__global__ __launch_bounds__(256) void k_bn_stats(const float* __restrict__ h,
                                                  float* __restrict__ sums, int N) {
  int c = threadIdx.x & 63;
  int rl = threadIdx.x >> 6;
  float s = 0.f, q = 0.f;
  for (int n = blockIdx.x * 4 + rl; n < N; n += gridDim.x * 4) {
    float v = h[(size_t)n * 64 + c];
    s += v;
    q += v * v;
  }
  __shared__ float ls[256], lq[256];
  ls[threadIdx.x] = s;
  lq[threadIdx.x] = q;
  __syncthreads();
  if (rl == 0) {
    s = ls[c] + ls[64 + c] + ls[128 + c] + ls[192 + c];
    q = lq[c] + lq[64 + c] + lq[128 + c] + lq[192 + c];
    atomicAdd(&sums[c], s);
    atomicAdd(&sums[64 + c], q);
  }
}

__global__ __launch_bounds__(256) void k_bn_apply(const float* __restrict__ gat,
                                                  const float* __restrict__ sums,
                                                  const float* __restrict__ g,
                                                  const float* __restrict__ be,
                                                  const float* __restrict__ resid,
                                                  float* __restrict__ out,
                                                  int total, float inv_n) {
  int idx = blockIdx.x * 256 + threadIdx.x;
  if (idx >= total) return;
  int c = idx & 63;
  float mu = sums[c] * inv_n;
  float var = sums[64 + c] * inv_n - mu * mu;
  float inv = rsqrtf(var + 1e-5f);
  float v = g[c] * (gat[idx] - mu) * inv + be[c];
  float ge = 0.5f * v * (1.f + erff(v * 0.70710678118654752f));
  out[idx] = ge + (resid ? resid[idx] : 0.f);
}

// ---------------- pooling + heads ----------------

__global__ __launch_bounds__(256) void k_pool(const float* __restrict__ h,
                                              const int* __restrict__ batch,
                                              float* __restrict__ pool, int total) {
  int idx = blockIdx.x * 256 + threadIdx.x;
  if (idx >= total) return;
  int n = idx >> 6, c = idx & 63;
  atomicAdd(&pool[(size_t)batch[n] * 64 + c], h[idx]);
}

__global__ void k_head(const float* __restrict__ pool, const float* __restrict__ Wmu,
                       const float* __restrict__ bmu, const float* __restrict__ Wlv,
                       const float* __restrict__ blv, float* __restrict__ out, int G) {
  int g = blockIdx.x;
  int c = threadIdx.x; // 64 threads
  __shared__ float row[64];
  row[c] = pool[(size_t)g * 64 + c];
  __syncthreads();
  float am = 0.f, al = 0.f;
  for (int k = 0; k < 64; ++k) {
    float r = row[k];
    am = fmaf(r, Wmu[k * 64 + c], am);
    al = fmaf(r, Wlv[k * 64 + c], al);
  }
  out[(size_t)g * 64 + c] = am + bmu[c];
  out[(size_t)G * 64 + (size_t)g * 64 + c] = al + blv[c];
}

// ---------------- launch ----------------

extern "C" void kernel_launch(void* const* d_in, const int* in_sizes, int n_in,
                              void* d_out, int out_size, void* d_ws, size_t ws_size,
                              hipStream_t stream) {
  const float* x    = (const float*)d_in[0];
  const int* esrc   = (const int*)d_in[1];
  const int* edst   = (const int*)d_in[2];
  const int* batch  = (const int*)d_in[3];
  const float* Wl[3]  = {(const float*)d_in[5],  (const float*)d_in[11], (const float*)d_in[17]};
  const float* Wr[3]  = {(const float*)d_in[6],  (const float*)d_in[12], (const float*)d_in[18]};
  const float* att[3] = {(const float*)d_in[7],  (const float*)d_in[13], (const float*)d_in[19]};
  const float* bia[3] = {(const float*)d_in[8],  (const float*)d_in[14], (const float*)d_in[20]};
  const float* gam[3] = {(const float*)d_in[9],  (const float*)d_in[15], (const float*)d_in[21]};
  const float* bet[3] = {(const float*)d_in[10], (const float*)d_in[16], (const float*)d_in[22]};
  const float* Wmu = (const float*)d_in[23];
  const float* bmu = (const float*)d_in[24];
  const float* Wlv = (const float*)d_in[25];
  const float* blv = (const float*)d_in[26];
  float* out = (float*)d_out;

  const int N = in_sizes[0] / 64;
  const int E = in_sizes[1];
  const int G = out_size / 128;

  char* p = (char*)d_ws;
  auto alloc = [&](size_t bytes) -> void* {
    void* r = (void*)p;
    p += (bytes + 255) & ~(size_t)255;
    return r;
  };
  unsigned short* xlb = (unsigned short*)alloc((size_t)N * 256 * 2);
  float* xr     = (float*)alloc((size_t)N * 256 * 4);
  float* hA     = (float*)alloc((size_t)N * 64 * 4);
  float* hB     = (float*)alloc((size_t)N * 64 * 4);
  float* gat    = (float*)alloc((size_t)N * 64 * 4);
  int*   rowptr = (int*)alloc((size_t)(N + 1) * 4);
  int*   cursor = (int*)alloc((size_t)N * 4);
  int*   deg    = (int*)alloc((size_t)N * 4);
  int*   bs     = (int*)alloc(256 * 4);
  int*   col    = (int*)alloc((size_t)E * 4);
  float* bnsum  = (float*)alloc(128 * 4);
  float* pool   = (float*)alloc((size_t)G * 64 * 4);

  const int nbN   = (N + 255) / 256;
  const int nbE   = (E + 255) / 256;
  const int nbGm  = (N + GR - 1) / GR;
  const int nbGat = (N + 3) / 4;
  const int nbEl  = (N * 64 + 255) / 256;
  const float inv_n = 1.f / (float)N;

  // ---- CSR build (dst identical for all layers) ----
  hipMemsetAsync(deg, 0, (size_t)N * 4, stream);
  k_degree<<<nbE, 256, 0, stream>>>(edst, deg, E);
  k_scan1<<<nbN, 256, 0, stream>>>(deg, rowptr, bs, N);
  k_scan2<<<1, 256, 0, stream>>>(bs, nbN);
  k_scan3<<<nbN, 256, 0, stream>>>(rowptr, bs, cursor, N, E);
  k_fill<<<nbE, 256, 0, stream>>>(esrc, edst, cursor, col, E);

  // ---- 3 GATv2 + BN + GELU (+res) layers ----
  const float* hin = x;
  float* houts[3] = {hA, hB, hA};
  for (int L = 0; L < 3; ++L) {
    float* hout = houts[L];
    const float* resid = (L == 0) ? nullptr : hin;
    k_gemm2<<<nbGm, 256, 0, stream>>>(hin, Wl[L], Wr[L], xlb, xr, N);
    k_gat<<<nbGat, 256, 0, stream>>>(xlb, xr, att[L], bia[L], rowptr, col, gat, N);
    hipMemsetAsync(bnsum, 0, 128 * 4, stream);
    k_bn_stats<<<256, 256, 0, stream>>>(gat, bnsum, N);
    k_bn_apply<<<nbEl, 256, 0, stream>>>(gat, bnsum, gam[L], bet[L], resid, hout, N * 64, inv_n);
    hin = hout;
  }

  // ---- pool + heads ----
  hipMemsetAsync(pool, 0, (size_t)G * 64 * 4, stream);
  k_pool<<<nbEl, 256, 0, stream>>>(hin, batch, pool, N * 64);
  k_head<<<G, 64, 0, stream>>>(pool, Wmu, bmu, Wlv, blv, out, G);
}

// Round 3
// 605.218 us; speedup vs baseline: 1.9148x; 1.2592x over previous
//
#include <hip/hip_runtime.h>
#include <math.h>

typedef __attribute__((ext_vector_type(8))) short bf16x8;
typedef __attribute__((ext_vector_type(4))) float f32x4;

static __device__ __forceinline__ unsigned short f2bf(float f) {
  unsigned u = __float_as_uint(f);
  unsigned r = (u + 0x7FFF + ((u >> 16) & 1)) >> 16; // RNE
  return (unsigned short)r;
}
static __device__ __forceinline__ float bf2f(unsigned short b) {
  return __uint_as_float(((unsigned)b) << 16);
}

// DPP add: x += lane-permuted x (ctrl must be an immediate)
#define DPP_ADD(x, ctrl) \
  ((x) + __int_as_float(__builtin_amdgcn_update_dpp(0, __float_as_int(x), (ctrl), 0xf, 0xf, false)))

// ---------------- CSR build ----------------

__global__ void k_degree(const int* __restrict__ dst, int* __restrict__ deg, int E) {
  int e = blockIdx.x * 256 + threadIdx.x;
  if (e < E) atomicAdd(&deg[dst[e]], 1);
}

__global__ void k_scan1(const int* __restrict__ deg, int* __restrict__ part,
                        int* __restrict__ bs, int N) {
  __shared__ int s[256];
  int gid = blockIdx.x * 256 + threadIdx.x;
  int v = (gid < N) ? deg[gid] : 0;
  s[threadIdx.x] = v;
  __syncthreads();
  for (int off = 1; off < 256; off <<= 1) {
    int t = (threadIdx.x >= off) ? s[threadIdx.x - off] : 0;
    __syncthreads();
    s[threadIdx.x] += t;
    __syncthreads();
  }
  if (gid < N) part[gid] = s[threadIdx.x] - v;
  if (threadIdx.x == 255) bs[blockIdx.x] = s[255];
}

__global__ void k_scan2(int* __restrict__ bs, int nb) {
  __shared__ int s[256];
  int v = (threadIdx.x < nb) ? bs[threadIdx.x] : 0;
  s[threadIdx.x] = v;
  __syncthreads();
  for (int off = 1; off < 256; off <<= 1) {
    int t = (threadIdx.x >= off) ? s[threadIdx.x - off] : 0;
    __syncthreads();
    s[threadIdx.x] += t;
    __syncthreads();
  }
  if (threadIdx.x < nb) bs[threadIdx.x] = s[threadIdx.x] - v;
}

__global__ void k_scan3(int* __restrict__ rowptr, const int* __restrict__ bs,
                        int* __restrict__ cursor, int N, int E) {
  int gid = blockIdx.x * 256 + threadIdx.x;
  if (gid < N) {
    int v = rowptr[gid] + bs[blockIdx.x];
    rowptr[gid] = v;
    cursor[gid] = v;
  }
  if (gid == 0) rowptr[N] = E;
}

__global__ void k_fill(const int* __restrict__ src, const int* __restrict__ dst,
                       int* __restrict__ cursor, int* __restrict__ colb, int E) {
  int e = blockIdx.x * 256 + threadIdx.x;
  if (e < E) {
    int p = atomicAdd(&cursor[dst[e]], 1);
    colb[p] = src[e] << 9; // byte offset into xlb rows (256 bf16 = 512 B)
  }
}

// ---------------- W prep: fp32 [64][256] -> bf16 hi/lo transposed [256][64] ----------------

__global__ __launch_bounds__(256) void k_wprep(const float* __restrict__ W0, const float* __restrict__ W1,
                                               const float* __restrict__ W2, const float* __restrict__ W3,
                                               const float* __restrict__ W4, const float* __restrict__ W5,
                                               unsigned short* __restrict__ wt) {
  int gid = blockIdx.x * 256 + threadIdx.x; // 6 * 16384
  int m = gid >> 14;
  int r = gid & 16383;
  int k = r >> 8;    // 0..63
  int n = r & 255;   // 0..255
  const float* W = (m == 0) ? W0 : (m == 1) ? W1 : (m == 2) ? W2
                 : (m == 3) ? W3 : (m == 4) ? W4 : W5;
  float v = W[k * 256 + n];
  unsigned short hi = f2bf(v);
  unsigned short lo = f2bf(v - bf2f(hi));
  unsigned short* base = wt + (size_t)m * 32768;
  base[n * 64 + k] = hi;
  base[16384 + n * 64 + k] = lo;
}

// ---------------- MFMA dual GEMM: out = h @ W (M=50k, K=64, N=256 per mat) ----------------
// grid (ceil(N/32), 4): y 0,1 -> Wl cols 0-127/128-255 -> xlb bf16; y 2,3 -> Wr -> xr f32.

__global__ __launch_bounds__(256) void k_mm(const float* __restrict__ h,
                                            const unsigned short* __restrict__ wtL,
                                            const unsigned short* __restrict__ wtR,
                                            unsigned short* __restrict__ xlb,
                                            float* __restrict__ xr, int N) {
  __shared__ unsigned short Ah[32][72], Al[32][72];
  __shared__ unsigned short Bh[128][72], Bl[128][72];
  const int t = threadIdx.x;
  const int r0 = blockIdx.x * 32;
  const bool isL = (blockIdx.y < 2);
  const unsigned short* wb = isL ? wtL : wtR;
  const int coff = (blockIdx.y & 1) * 128;

  // stage A (fp32 -> bf16 hi/lo)
  {
    int row = t >> 3, c0 = (t & 7) * 8;
    int gr = r0 + row;
    float4 v0 = {0, 0, 0, 0}, v1 = {0, 0, 0, 0};
    if (gr < N) {
      v0 = *(const float4*)(h + (size_t)gr * 64 + c0);
      v1 = *(const float4*)(h + (size_t)gr * 64 + c0 + 4);
    }
    float vs[8] = {v0.x, v0.y, v0.z, v0.w, v1.x, v1.y, v1.z, v1.w};
    bf16x8 hi8, lo8;
#pragma unroll
    for (int i = 0; i < 8; ++i) {
      unsigned short hh = f2bf(vs[i]);
      hi8[i] = (short)hh;
      lo8[i] = (short)f2bf(vs[i] - bf2f(hh));
    }
    *(bf16x8*)&Ah[row][c0] = hi8;
    *(bf16x8*)&Al[row][c0] = lo8;
  }
  // stage B (already bf16 hi/lo, transposed [n][k])
#pragma unroll
  for (int j = 0; j < 4; ++j) {
    int cidx = t + 256 * j;       // 0..1023 chunks of 8
    int n = cidx >> 3, k0 = (cidx & 7) * 8;
    const unsigned short* src = wb + (size_t)(coff + n) * 64 + k0;
    *(bf16x8*)&Bh[n][k0] = *(const bf16x8*)src;
    *(bf16x8*)&Bl[n][k0] = *(const bf16x8*)(src + 16384);
  }
  __syncthreads();

  const int wave = t >> 6, lane = t & 63;
  const int rw = (wave & 1) * 16, cw = (wave >> 1) * 64;
  const int m15 = lane & 15, quad = lane >> 4;
  f32x4 acc[4] = {{0, 0, 0, 0}, {0, 0, 0, 0}, {0, 0, 0, 0}, {0, 0, 0, 0}};
#pragma unroll
  for (int kk = 0; kk < 64; kk += 32) {
    bf16x8 ah = *(const bf16x8*)&Ah[rw + m15][kk + quad * 8];
    bf16x8 al = *(const bf16x8*)&Al[rw + m15][kk + quad * 8];
#pragma unroll
    for (int s = 0; s < 4; ++s) {
      int n = cw + s * 16 + m15;
      bf16x8 bh = *(const bf16x8*)&Bh[n][kk + quad * 8];
      bf16x8 bl = *(const bf16x8*)&Bl[n][kk + quad * 8];
      acc[s] = __builtin_amdgcn_mfma_f32_16x16x32_bf16(ah, bh, acc[s], 0, 0, 0);
      acc[s] = __builtin_amdgcn_mfma_f32_16x16x32_bf16(al, bh, acc[s], 0, 0, 0);
      acc[s] = __builtin_amdgcn_mfma_f32_16x16x32_bf16(ah, bl, acc[s], 0, 0, 0);
    }
  }
  // C/D layout: col = lane&15, row = quad*4 + reg
#pragma unroll
  for (int s = 0; s < 4; ++s) {
#pragma unroll
    for (int r = 0; r < 4; ++r) {
      int row_g = r0 + rw + quad * 4 + r;
      if (row_g < N) {
        int col_g = coff + cw + s * 16 + m15; // 0..255 within this mat
        if (isL) xlb[(size_t)row_g * 256 + col_g] = f2bf(acc[s][r]);
        else     xr[(size_t)row_g * 256 + col_g] = acc[s][r];
      }
    }
  }
}

// ---------------- GATv2: wave per node, head-major lanes, DPP reduce, exp2 softmax ----------------

__global__ __launch_bounds__(256) void k_gat(const unsigned short* __restrict__ xlb,
                                             const float* __restrict__ xr,
                                             const float* __restrict__ att,
                                             const float* __restrict__ bias,
                                             const int* __restrict__ rowptr,
                                             const int* __restrict__ colb,
                                             float* __restrict__ out, int N) {
  int node = blockIdx.x * 4 + (threadIdx.x >> 6);
  int lane = threadIdx.x & 63;
  if (node >= N) return;
  float4 a4 = *(const float4*)(att + lane * 4);
  const float LOG2E = 1.4426950408889634f;
  a4.x *= LOG2E; a4.y *= LOG2E; a4.z *= LOG2E; a4.w *= LOG2E;
  const float4 xr4 = *(const float4*)(xr + (size_t)node * 256 + lane * 4);
  int beg = rowptr[node], end = rowptr[node + 1];
  const char* base = (const char*)xlb + (size_t)lane * 8;
  float m = -INFINITY, lsum = 0.f;
  float ox = 0.f, oy = 0.f, oz = 0.f, ow = 0.f;
  uint2 vb_next = *(const uint2*)(base + (size_t)(unsigned)node * 512);
  int off_n = (beg < end) ? colb[beg] : 0;
  for (int e = beg; e <= end; ++e) {
    uint2 vb = vb_next;
    int off = off_n;
    if (e + 1 < end) off_n = colb[e + 1];
    if (e < end) vb_next = *(const uint2*)(base + (size_t)(unsigned)off);
    float vx = __uint_as_float(vb.x << 16);
    float vy = __uint_as_float(vb.x & 0xFFFF0000u);
    float vz = __uint_as_float(vb.y << 16);
    float vw = __uint_as_float(vb.y & 0xFFFF0000u);
    float sx = vx + xr4.x, sy = vy + xr4.y, sz = vz + xr4.z, sw = vw + xr4.w;
    sx = fmaxf(sx, 0.2f * sx);
    sy = fmaxf(sy, 0.2f * sy);
    sz = fmaxf(sz, 0.2f * sz);
    sw = fmaxf(sw, 0.2f * sw);
    float p1 = fmaf(sy, a4.y, sx * a4.x);
    float p2 = fmaf(sw, a4.w, sz * a4.z);
    float p = p1 + p2;
    // sum over the 16-lane head group, pure VALU (quad_perm xor1, xor2; row_ror 4, 8)
    p = DPP_ADD(p, 0xB1);
    p = DPP_ADD(p, 0x4E);
    p = DPP_ADD(p, 0x124);
    p = DPP_ADD(p, 0x128);
    float nm = fmaxf(m, p);
    float sc = __builtin_amdgcn_exp2f(m - nm);
    float w = __builtin_amdgcn_exp2f(p - nm);
    lsum = fmaf(lsum, sc, w);
    ox = fmaf(ox, sc, w * vx);
    oy = fmaf(oy, sc, w * vy);
    oz = fmaf(oz, sc, w * vz);
    ow = fmaf(ow, sc, w * vw);
    m = nm;
  }
  float inv = __builtin_amdgcn_rcpf(lsum);
  float rx = ox * inv, ry = oy * inv, rz = oz * inv, rw = ow * inv;
  rx += __shfl_xor(rx, 16, 64); rx += __shfl_xor(rx, 32, 64);
  ry += __shfl_xor(ry, 16, 64); ry += __shfl_xor(ry, 32, 64);
  rz += __shfl_xor(rz, 16, 64); rz += __shfl_xor(rz, 32, 64);
  rw += __shfl_xor(rw, 16, 64); rw += __shfl_xor(rw, 32, 64);
  if (lane < 16) {
    float4 b4 = *(const float4*)(bias + lane * 4);
    float4 res;
    res.x = 0.25f * rx + b4.x;
    res.y = 0.25f * ry + b4.y;
    res.z = 0.25f * rz + b4.z;
    res.w = 0.25f * rw + b4.w;
    *(float4*)(out + (size_t)node * 64 + lane * 4) = res;
  }
}

// ---------------- BN stats + apply (+GELU +residual) ----------------

__global__ __launch_bounds__(256) void k_bn_stats(const float* __restrict__ h,
                                                  float* __restrict__ sums, int N) {
  int c = threadIdx.x & 63;
  int rl = threadIdx.x >> 6;
  float s = 0.f, q = 0.f;
  for (int n = blockIdx.x * 4 + rl; n < N; n += gridDim.x * 4) {
    float v = h[(size_t)n * 64 + c];
    s += v;
    q += v * v;
  }
  __shared__ float ls[256], lq[256];
  ls[threadIdx.x] = s;
  lq[threadIdx.x] = q;
  __syncthreads();
  if (rl == 0) {
    s = ls[c] + ls[64 + c] + ls[128 + c] + ls[192 + c];
    q = lq[c] + lq[64 + c] + lq[128 + c] + lq[192 + c];
    atomicAdd(&sums[c], s);
    atomicAdd(&sums[64 + c], q);
  }
}

__global__ __launch_bounds__(256) void k_bn_apply(const float* __restrict__ gat,
                                                  const float* __restrict__ sums,
                                                  const float* __restrict__ g,
                                                  const float* __restrict__ be,
                                                  const float* __restrict__ resid,
                                                  float* __restrict__ out,
                                                  int total, float inv_n) {
  int idx = blockIdx.x * 256 + threadIdx.x;
  if (idx >= total) return;
  int c = idx & 63;
  float mu = sums[c] * inv_n;
  float var = sums[64 + c] * inv_n - mu * mu;
  float inv = rsqrtf(var + 1e-5f);
  float v = g[c] * (gat[idx] - mu) * inv + be[c];
  float ge = 0.5f * v * (1.f + erff(v * 0.70710678118654752f));
  out[idx] = ge + (resid ? resid[idx] : 0.f);
}

// ---------------- pooling + heads ----------------

__global__ __launch_bounds__(256) void k_pool(const float* __restrict__ h,
                                              const int* __restrict__ batch,
                                              float* __restrict__ pool, int total) {
  int idx = blockIdx.x * 256 + threadIdx.x;
  if (idx >= total) return;
  int n = idx >> 6, c = idx & 63;
  atomicAdd(&pool[(size_t)batch[n] * 64 + c], h[idx]);
}

__global__ void k_head(const float* __restrict__ pool, const float* __restrict__ Wmu,
                       const float* __restrict__ bmu, const float* __restrict__ Wlv,
                       const float* __restrict__ blv, float* __restrict__ out, int G) {
  int g = blockIdx.x;
  int c = threadIdx.x; // 64 threads
  __shared__ float row[64];
  row[c] = pool[(size_t)g * 64 + c];
  __syncthreads();
  float am = 0.f, al = 0.f;
  for (int k = 0; k < 64; ++k) {
    float r = row[k];
    am = fmaf(r, Wmu[k * 64 + c], am);
    al = fmaf(r, Wlv[k * 64 + c], al);
  }
  out[(size_t)g * 64 + c] = am + bmu[c];
  out[(size_t)G * 64 + (size_t)g * 64 + c] = al + blv[c];
}

// ---------------- launch ----------------

extern "C" void kernel_launch(void* const* d_in, const int* in_sizes, int n_in,
                              void* d_out, int out_size, void* d_ws, size_t ws_size,
                              hipStream_t stream) {
  const float* x    = (const float*)d_in[0];
  const int* esrc   = (const int*)d_in[1];
  const int* edst   = (const int*)d_in[2];
  const int* batch  = (const int*)d_in[3];
  const float* Wl[3]  = {(const float*)d_in[5],  (const float*)d_in[11], (const float*)d_in[17]};
  const float* Wr[3]  = {(const float*)d_in[6],  (const float*)d_in[12], (const float*)d_in[18]};
  const float* att[3] = {(const float*)d_in[7],  (const float*)d_in[13], (const float*)d_in[19]};
  const float* bia[3] = {(const float*)d_in[8],  (const float*)d_in[14], (const float*)d_in[20]};
  const float* gam[3] = {(const float*)d_in[9],  (const float*)d_in[15], (const float*)d_in[21]};
  const float* bet[3] = {(const float*)d_in[10], (const float*)d_in[16], (const float*)d_in[22]};
  const float* Wmu = (const float*)d_in[23];
  const float* bmu = (const float*)d_in[24];
  const float* Wlv = (const float*)d_in[25];
  const float* blv = (const float*)d_in[26];
  float* out = (float*)d_out;

  const int N = in_sizes[0] / 64;
  const int E = in_sizes[1];
  const int G = out_size / 128;

  char* p = (char*)d_ws;
  auto alloc = [&](size_t bytes) -> void* {
    void* r = (void*)p;
    p += (bytes + 255) & ~(size_t)255;
    return r;
  };
  // zero-init region first (one memset covers deg + bnsum + pool)
  int*   deg    = (int*)alloc((size_t)N * 4);
  float* bnsum  = (float*)alloc(3 * 128 * 4);
  float* pool   = (float*)alloc((size_t)G * 64 * 4);
  char*  zend   = p;
  unsigned short* xlb = (unsigned short*)alloc((size_t)N * 256 * 2);
  float* xr     = (float*)alloc((size_t)N * 256 * 4);
  float* hA     = (float*)alloc((size_t)N * 64 * 4);
  float* hB     = (float*)alloc((size_t)N * 64 * 4);
  float* gat    = (float*)alloc((size_t)N * 64 * 4);
  int*   rowptr = (int*)alloc((size_t)(N + 1) * 4);
  int*   cursor = (int*)alloc((size_t)N * 4);
  int*   bs     = (int*)alloc(256 * 4);
  int*   colb   = (int*)alloc((size_t)E * 4);
  unsigned short* wt = (unsigned short*)alloc(6 * 32768 * 2);

  const int nbN   = (N + 255) / 256;
  const int nbE   = (E + 255) / 256;
  const int nbGat = (N + 3) / 4;
  const int nbEl  = (N * 64 + 255) / 256;
  const int nbMm  = (N + 31) / 32;
  const float inv_n = 1.f / (float)N;

  hipMemsetAsync(deg, 0, (size_t)(zend - (char*)deg), stream);

  // ---- W prep + CSR build ----
  k_wprep<<<6 * 64, 256, 0, stream>>>(Wl[0], Wr[0], Wl[1], Wr[1], Wl[2], Wr[2], wt);
  k_degree<<<nbE, 256, 0, stream>>>(edst, deg, E);
  k_scan1<<<nbN, 256, 0, stream>>>(deg, rowptr, bs, N);
  k_scan2<<<1, 256, 0, stream>>>(bs, nbN);
  k_scan3<<<nbN, 256, 0, stream>>>(rowptr, bs, cursor, N, E);
  k_fill<<<nbE, 256, 0, stream>>>(esrc, edst, cursor, colb, E);

  // wt layout: mat (L*2 + 0/1) at wt + midx*32768
  const unsigned short* wtL[3] = {wt, wt + 2 * 32768, wt + 4 * 32768};
  const unsigned short* wtR[3] = {wt + 32768, wt + 3 * 32768, wt + 5 * 32768};

  // ---- 3 GATv2 + BN + GELU (+res) layers ----
  const float* hin = x;
  float* houts[3] = {hA, hB, hA};
  for (int L = 0; L < 3; ++L) {
    float* hout = houts[L];
    const float* resid = (L == 0) ? nullptr : hin;
    dim3 gmm(nbMm, 4);
    k_mm<<<gmm, 256, 0, stream>>>(hin, wtL[L], wtR[L], xlb, xr, N);
    k_gat<<<nbGat, 256, 0, stream>>>(xlb, xr, att[L], bia[L], rowptr, colb, gat, N);
    k_bn_stats<<<256, 256, 0, stream>>>(gat, bnsum + 128 * L, N);
    k_bn_apply<<<nbEl, 256, 0, stream>>>(gat, bnsum + 128 * L, gam[L], bet[L], resid, hout,
                                         N * 64, inv_n);
    hin = hout;
  }

  // ---- pool + heads ----
  k_pool<<<nbEl, 256, 0, stream>>>(hin, batch, pool, N * 64);
  k_head<<<G, 64, 0, stream>>>(pool, Wmu, bmu, Wlv, blv, out, G);
}